// Round 1
// baseline (1508.154 us; speedup 1.0000x reference)
//
#include <hip/hip_runtime.h>

#define B_ 8
#define S_ 4096
#define E_ 1024
#define H_ 128
#define M_ (B_*S_)

static constexpr float QSCALE = 0.08838834764831845f; // 1/sqrt(128)

// ---------------- QKV projection ----------------
// grid (M_/32, 3), block 128. Each block: 32 rows x 128 cols of one of Q/K/V.
__global__ __launch_bounds__(128)
void qkv_proj_kernel(const float* __restrict__ x,
                     const float* __restrict__ Wq,
                     const float* __restrict__ Wk,
                     const float* __restrict__ Wv,
                     float* __restrict__ Qo,
                     float* __restrict__ Ko,
                     float* __restrict__ Vo)
{
    const int t  = threadIdx.x;        // 0..127
    const int rb = blockIdx.x;         // row block (32 rows)
    const int which = blockIdx.y;      // 0=Q,1=K,2=V
    const float* __restrict__ W = (which==0)?Wq:((which==1)?Wk:Wv);
    float* __restrict__ O = (which==0)?Qo:((which==1)?Ko:Vo);
    const float scale = (which==0)? QSCALE : 1.0f;

    __shared__ float xsT[32][36];      // [kk][r], pad 36 keeps b128 16B-aligned
    __shared__ float ws[32][128];      // [kk][h]

    const int rg = t >> 5;             // 0..3 -> rows rg*8 .. rg*8+7
    const int hg = t & 31;             // cols hg*4 .. hg*4+3
    const int row0 = rb*32;

    float acc[8][4];
    #pragma unroll
    for (int i=0;i<8;++i)
        #pragma unroll
        for (int j=0;j<4;++j) acc[i][j]=0.f;

    for (int k0=0; k0<E_; k0+=32) {
        __syncthreads();
        // stage x tile, transposed: xsT[kk][r]
        #pragma unroll
        for (int i=0;i<8;++i) {
            int idx = i*128 + t;
            int kk = idx & 31, r = idx >> 5;
            xsT[kk][r] = x[(size_t)(row0+r)*E_ + k0 + kk];
        }
        // stage W tile: ws[kk][h] via float4
        #pragma unroll
        for (int i=0;i<8;++i) {
            int idx = i*128 + t;
            int kk = idx >> 5, h4 = idx & 31;
            *(float4*)&ws[kk][h4*4] = *(const float4*)&W[(size_t)(k0+kk)*H_ + h4*4];
        }
        __syncthreads();
        #pragma unroll
        for (int kk=0; kk<32; ++kk) {
            float4 wv = *(float4*)&ws[kk][hg*4];
            float4 xa = *(float4*)&xsT[kk][rg*8];
            float4 xb = *(float4*)&xsT[kk][rg*8+4];
            float xr[8] = {xa.x,xa.y,xa.z,xa.w,xb.x,xb.y,xb.z,xb.w};
            float wr[4] = {wv.x,wv.y,wv.z,wv.w};
            #pragma unroll
            for (int i=0;i<8;++i)
                #pragma unroll
                for (int j=0;j<4;++j)
                    acc[i][j] += xr[i]*wr[j];
        }
    }
    #pragma unroll
    for (int i=0;i<8;++i) {
        float4 o;
        o.x = acc[i][0]*scale; o.y = acc[i][1]*scale;
        o.z = acc[i][2]*scale; o.w = acc[i][3]*scale;
        *(float4*)&O[(size_t)(row0 + rg*8 + i)*H_ + hg*4] = o;
    }
}

// ---------------- Flash attention (fp32, causal) ----------------
// grid (S_/32, B_), block 256. Each block: 32 query rows of one batch.
__global__ __launch_bounds__(256)
void attn_kernel(const float* __restrict__ Q,
                 const float* __restrict__ K,
                 const float* __restrict__ V,
                 float* __restrict__ Out)
{
    const int t  = threadIdx.x;
    const int qt = (S_/32 - 1) - blockIdx.x;  // reverse order: big blocks first
    const int b  = blockIdx.y;
    const float* __restrict__ Qb = Q + (size_t)b*S_*H_;
    const float* __restrict__ Kb = K + (size_t)b*S_*H_;
    const float* __restrict__ Vb = V + (size_t)b*S_*H_;
    float* __restrict__ Ob = Out + (size_t)b*S_*H_;

    __shared__ float Qs[32][132];
    __shared__ float Ks[32][132];
    __shared__ float Vs[32][132];
    __shared__ float Ss[32][33];
    __shared__ float PsT[32][36];   // [c][r], pad 36 -> b128-aligned rows
    __shared__ float mrow[32], lrow[32], arow[32];

    const int q0 = qt*32;

    // load Q tile
    #pragma unroll
    for (int i=0;i<4;++i) {
        int idx = i*256 + t;
        int r = idx >> 5, h4 = idx & 31;
        *(float4*)&Qs[r][h4*4] = *(const float4*)&Qb[(size_t)(q0+r)*H_ + h4*4];
    }
    if (t < 32) { mrow[t] = -1e30f; lrow[t] = 0.f; }

    // S-phase mapping: rows {2*srg, 2*srg+1}, cols {scg, scg+16}
    const int srg = t >> 4;       // 0..15
    const int scg = t & 15;       // 0..15
    // PV mapping: rows prg*4..+3, cols phg*4..+3
    const int prg = t >> 5;       // 0..7
    const int phg = t & 31;       // 0..31

    float oacc[4][4];
    #pragma unroll
    for (int i=0;i<4;++i)
        #pragma unroll
        for (int j=0;j<4;++j) oacc[i][j]=0.f;

    const int nkt = qt + 1;
    for (int kt=0; kt<nkt; ++kt) {
        __syncthreads();  // prior PV done before K/V overwrite
        #pragma unroll
        for (int i=0;i<4;++i) {
            int idx = i*256 + t;
            int c = idx >> 5, h4 = idx & 31;
            *(float4*)&Ks[c][h4*4] = *(const float4*)&Kb[(size_t)(kt*32+c)*H_ + h4*4];
            *(float4*)&Vs[c][h4*4] = *(const float4*)&Vb[(size_t)(kt*32+c)*H_ + h4*4];
        }
        __syncthreads();

        // ---- S = Q K^T (2x2 micro-tile) ----
        const int r0 = 2*srg, r1 = r0+1, c0 = scg, c1 = scg+16;
        float s00=0.f, s01=0.f, s10=0.f, s11=0.f;
        for (int h4=0; h4<32; ++h4) {
            float4 qa = *(float4*)&Qs[r0][h4*4];
            float4 qb = *(float4*)&Qs[r1][h4*4];
            float4 ka = *(float4*)&Ks[c0][h4*4];
            float4 kb = *(float4*)&Ks[c1][h4*4];
            s00 += qa.x*ka.x + qa.y*ka.y + qa.z*ka.z + qa.w*ka.w;
            s01 += qa.x*kb.x + qa.y*kb.y + qa.z*kb.z + qa.w*kb.w;
            s10 += qb.x*ka.x + qb.y*ka.y + qb.z*ka.z + qb.w*ka.w;
            s11 += qb.x*kb.x + qb.y*kb.y + qb.z*kb.z + qb.w*kb.w;
        }
        if (kt == qt) {  // diagonal tile: causal mask (k <= q)
            if (c0 > r0) s00 = -1e30f;
            if (c1 > r0) s01 = -1e30f;
            if (c0 > r1) s10 = -1e30f;
            if (c1 > r1) s11 = -1e30f;
        }
        Ss[r0][c0] = s00; Ss[r0][c1] = s01;
        Ss[r1][c0] = s10; Ss[r1][c1] = s11;
        __syncthreads();

        // ---- online softmax (one lane per row) ----
        if (t < 32) {
            const int r = t;
            float mo = mrow[r];
            float pm = mo;
            #pragma unroll
            for (int c=0;c<32;++c) pm = fmaxf(pm, Ss[r][c]);
            float alpha = __expf(mo - pm);
            float ls = 0.f;
            #pragma unroll
            for (int c=0;c<32;++c) {
                float p = __expf(Ss[r][c] - pm);
                PsT[c][r] = p;
                ls += p;
            }
            lrow[r] = lrow[r]*alpha + ls;
            mrow[r] = pm;
            arow[r] = alpha;
        }
        __syncthreads();

        // ---- O = O*alpha + P V (4x4 micro-tile) ----
        float a[4];
        #pragma unroll
        for (int i=0;i<4;++i) a[i] = arow[prg*4+i];
        #pragma unroll
        for (int i=0;i<4;++i)
            #pragma unroll
            for (int j=0;j<4;++j) oacc[i][j] *= a[i];
        #pragma unroll
        for (int kk=0; kk<32; ++kk) {
            float4 pv = *(float4*)&PsT[kk][prg*4];
            float4 vv = *(float4*)&Vs[kk][phg*4];
            float p[4] = {pv.x,pv.y,pv.z,pv.w};
            float v[4] = {vv.x,vv.y,vv.z,vv.w};
            #pragma unroll
            for (int i=0;i<4;++i)
                #pragma unroll
                for (int j=0;j<4;++j)
                    oacc[i][j] += p[i]*v[j];
        }
    }

    // epilogue: divide by l, store
    float linv[4];
    #pragma unroll
    for (int i=0;i<4;++i) linv[i] = 1.0f / lrow[prg*4+i];
    #pragma unroll
    for (int i=0;i<4;++i) {
        float4 o;
        o.x = oacc[i][0]*linv[i]; o.y = oacc[i][1]*linv[i];
        o.z = oacc[i][2]*linv[i]; o.w = oacc[i][3]*linv[i];
        *(float4*)&Ob[(size_t)(q0 + prg*4 + i)*H_ + phg*4] = o;
    }
}

extern "C" void kernel_launch(void* const* d_in, const int* in_sizes, int n_in,
                              void* d_out, int out_size, void* d_ws, size_t ws_size,
                              hipStream_t stream) {
    const float* x  = (const float*)d_in[0];
    const float* Wq = (const float*)d_in[1];
    const float* Wk = (const float*)d_in[2];
    const float* Wv = (const float*)d_in[3];
    float* out = (float*)d_out;

    float* Qw = (float*)d_ws;
    float* Kw = Qw + (size_t)M_*H_;
    float* Vw = Kw + (size_t)M_*H_;

    dim3 gp(M_/32, 3);
    qkv_proj_kernel<<<gp, 128, 0, stream>>>(x, Wq, Wk, Wv, Qw, Kw, Vw);

    dim3 ga(S_/32, B_);
    attn_kernel<<<ga, 256, 0, stream>>>(Qw, Kw, Vw, out);
}

// Round 4
// 211.134 us; speedup vs baseline: 7.1431x; 7.1431x over previous
//
// v2.1 — identical algorithm to v2.0; resubmitted after infra failure (dead container x2)
#include <hip/hip_runtime.h>
#include <stdint.h>

#define B_ 8
#define S_ 4096
#define E_ 1024
#define H_ 128
#define M_ (B_*S_)

typedef __attribute__((ext_vector_type(8))) short short8;
typedef __attribute__((ext_vector_type(4))) float f32x4;

static constexpr float QSCALE = 0.08838834764831845f; // 1/sqrt(128)

__device__ __forceinline__ unsigned short f2bf(float f) {
    uint32_t u = __float_as_uint(f);
    u += 0x7fffu + ((u >> 16) & 1u);
    return (unsigned short)(u >> 16);
}

// ---------------- W transpose + bf16 convert: Wt[3][128][1024] ----------------
__global__ __launch_bounds__(256)
void prep_w_kernel(const float* __restrict__ Wq, const float* __restrict__ Wk,
                   const float* __restrict__ Wv, unsigned short* __restrict__ Wt)
{
    int id = blockIdx.x*256 + threadIdx.x;        // 0..49151
    int which = id >> 14;                          // 16384 chunks per weight
    int rem = id & 16383;
    int h = rem >> 7, kc = rem & 127;
    const float* __restrict__ W = (which==0)?Wq:((which==1)?Wk:Wv);
    const float scale = (which==0)? QSCALE : 1.0f;
    uint32_t u[4];
    #pragma unroll
    for (int p=0;p<4;++p) {
        unsigned short a = f2bf(W[(size_t)(kc*8 + 2*p  )*H_ + h] * scale);
        unsigned short b = f2bf(W[(size_t)(kc*8 + 2*p+1)*H_ + h] * scale);
        u[p] = (uint32_t)a | ((uint32_t)b << 16);
    }
    uint4 v; v.x=u[0]; v.y=u[1]; v.z=u[2]; v.w=u[3];
    *(uint4*)(Wt + (size_t)(which*H_ + h)*E_ + kc*8) = v;
}

// ---------------- QKV projection, bf16 MFMA ----------------
// grid (M_/128, 3), block 256 (4 waves). BM=128, BN=128, BK=64.
__global__ __launch_bounds__(256)
void proj_kernel(const float* __restrict__ x, const unsigned short* __restrict__ Wt,
                 unsigned short* __restrict__ Qg, unsigned short* __restrict__ Kg,
                 unsigned short* __restrict__ Vtg)
{
    const int t = threadIdx.x;
    const int w = t >> 6, l = t & 63;
    const int grp = l >> 4, li = l & 15;
    const int rb = blockIdx.x;
    const int which = blockIdx.y;
    const int row0 = rb * 128;

    __shared__ __align__(128) unsigned char smem[34816];
    unsigned char* sX = smem;            // [128][64] bf16, 128B rows, swizzled
    unsigned char* sW = smem + 16384;    // [128h][64k] bf16, swizzled
    unsigned char* epi = smem;           // epilogue union: 4 x [32][136] u16

    const unsigned char* Wslice = (const unsigned char*)(Wt + (size_t)which*H_*E_);

    f32x4 acc[2][8];
    const f32x4 zz = {0.f,0.f,0.f,0.f};
    #pragma unroll
    for (int mt=0;mt<2;++mt)
        #pragma unroll
        for (int nt=0;nt<8;++nt) acc[mt][nt] = zz;

    for (int k0=0; k0<E_; k0+=64) {
        __syncthreads();
        // stage x tile [128][64] fp32 -> bf16, swizzled
        #pragma unroll
        for (int i=0;i<8;++i) {
            int idx = i*256 + t;
            int row = idx >> 4, c4 = idx & 15;
            float4 v = *(const float4*)(x + (size_t)(row0+row)*E_ + k0 + c4*4);
            uint32_t lo = (uint32_t)f2bf(v.x) | ((uint32_t)f2bf(v.y)<<16);
            uint32_t hi = (uint32_t)f2bf(v.z) | ((uint32_t)f2bf(v.w)<<16);
            uint2 pv; pv.x = lo; pv.y = hi;
            *(uint2*)(sX + row*128 + ((c4*8) ^ ((row&7)<<4))) = pv;
        }
        // stage Wt slice [128][64] bf16, swizzled
        #pragma unroll
        for (int i=0;i<4;++i) {
            int c = i*256 + t;
            int h = c >> 3, cb = (c & 7) * 16;
            uint4 v = *(const uint4*)(Wslice + (size_t)h*2048 + k0*2 + cb);
            *(uint4*)(sW + h*128 + (cb ^ ((h&7)<<4))) = v;
        }
        __syncthreads();
        #pragma unroll
        for (int ks=0;ks<2;++ks) {
            short8 af[2], bf[8];
            #pragma unroll
            for (int mt=0;mt<2;++mt) {
                int row = w*32 + mt*16 + li;
                af[mt] = *(const short8*)(sX + row*128 + ((ks*64 + grp*16) ^ ((row&7)<<4)));
            }
            #pragma unroll
            for (int nt=0;nt<8;++nt) {
                int rh = nt*16 + li;
                bf[nt] = *(const short8*)(sW + rh*128 + ((ks*64 + grp*16) ^ ((rh&7)<<4)));
            }
            #pragma unroll
            for (int mt=0;mt<2;++mt)
                #pragma unroll
                for (int nt=0;nt<8;++nt)
                    acc[mt][nt] = __builtin_amdgcn_mfma_f32_16x16x32_bf16(af[mt], bf[nt], acc[mt][nt], 0,0,0);
        }
    }

    // epilogue via LDS: stage wave's 32x128 bf16 tile
    __syncthreads();
    const int base = w * 8704;  // 32*136*2
    #pragma unroll
    for (int mt=0;mt<2;++mt)
        #pragma unroll
        for (int nt=0;nt<8;++nt)
            #pragma unroll
            for (int r=0;r<4;++r) {
                int rowl = mt*16 + grp*4 + r;
                int col  = nt*16 + li;
                *(unsigned short*)(epi + base + rowl*272 + col*2) = f2bf(acc[mt][nt][r]);
            }
    __syncthreads();

    if (which < 2) {
        unsigned short* O = (which==0)? Qg : Kg;
        #pragma unroll
        for (int i=0;i<8;++i) {
            int idx = i*64 + l;
            int rowl = idx >> 4, cc = idx & 15;
            uint4 v = *(const uint4*)(epi + base + rowl*272 + cc*16);
            int row_g = row0 + w*32 + rowl;
            *(uint4*)((unsigned char*)O + (size_t)row_g*256 + cc*16) = v;
        }
    } else {
        // V: write transposed Vt[b][h][s] bf16
        const int bidx = rb >> 5;                 // 32 blocks per batch
        const int srow = (rb & 31) * 128 + w*32;  // s base within batch
        #pragma unroll
        for (int i=0;i<8;++i) {
            int idx = i*64 + l;
            int h = idx >> 2, sc = idx & 3;
            uint32_t u[4];
            #pragma unroll
            for (int p=0;p<4;++p) {
                unsigned short a = *(const unsigned short*)(epi + base + (sc*8 + 2*p  )*272 + h*2);
                unsigned short b = *(const unsigned short*)(epi + base + (sc*8 + 2*p+1)*272 + h*2);
                u[p] = (uint32_t)a | ((uint32_t)b << 16);
            }
            uint4 v; v.x=u[0]; v.y=u[1]; v.z=u[2]; v.w=u[3];
            *(uint4*)(Vtg + (size_t)(bidx*H_ + h)*S_ + srow + sc*8) = v;
        }
    }
}

// ---------------- Flash attention, bf16 MFMA ----------------
// grid (S_/64, B_), block 256 (4 waves). Q-tile 64 (16 rows/wave), KV-tile 64.
__global__ __launch_bounds__(256)
void attn_kernel(const unsigned short* __restrict__ Qg,
                 const unsigned short* __restrict__ Kg,
                 const unsigned short* __restrict__ Vtg,
                 float* __restrict__ Out)
{
    const int t = threadIdx.x;
    const int w = t >> 6, l = t & 63;
    const int grp = l >> 4, li = l & 15;
    const int qt = (S_/64 - 1) - blockIdx.x;  // reverse: long blocks first
    const int b  = blockIdx.y;
    const int q0 = qt * 64;

    __shared__ __align__(128) unsigned char sK[16384];  // [64][128] bf16 rows 256B, swz
    __shared__ __align__(128) unsigned char sV[16384];  // Vt [128h][64s] bf16 rows 128B, swz

    const size_t bbase = (size_t)b * S_ * H_;

    // Q fragments in registers (row = q0 + w*16 + li)
    short8 qf[4];
    {
        const unsigned short* qrow = Qg + bbase + (size_t)(q0 + w*16 + li) * H_;
        #pragma unroll
        for (int ks=0;ks<4;++ks)
            qf[ks] = *(const short8*)(qrow + ks*32 + grp*8);
    }

    const f32x4 zz = {0.f,0.f,0.f,0.f};
    f32x4 oacc[8];
    #pragma unroll
    for (int nt=0;nt<8;++nt) oacc[nt] = zz;
    float mrun = -1e30f, lrun = 0.f;

    const unsigned char* Kb = (const unsigned char*)(Kg + bbase);
    const unsigned char* Vb = (const unsigned char*)(Vtg + (size_t)b*H_*S_);
    const int srcBase = (l & 48) + ((l & 48) >> 2);

    for (int kt=0; kt<=qt; ++kt) {
        __syncthreads();
        // stage K tile [64][128] bf16 swizzled
        #pragma unroll
        for (int i=0;i<4;++i) {
            int c = i*256 + t;
            int row = c >> 4, cb = (c & 15) * 16;
            uint4 v = *(const uint4*)(Kb + (size_t)(kt*64 + row)*256 + cb);
            *(uint4*)(sK + row*256 + (cb ^ ((row&7)<<4))) = v;
        }
        // stage Vt tile [128][64] bf16 swizzled
        #pragma unroll
        for (int i=0;i<4;++i) {
            int c = i*256 + t;
            int h = c >> 3, cb = (c & 7) * 16;
            uint4 v = *(const uint4*)(Vb + (size_t)h*(S_*2) + kt*128 + cb);
            *(uint4*)(sV + h*128 + (cb ^ ((h&7)<<4))) = v;
        }
        __syncthreads();

        // ---- S^T = K · Q^T : lane holds S[q=li][key = mt*16+grp*4+r] ----
        f32x4 sacc[4];
        #pragma unroll
        for (int mt=0;mt<4;++mt) sacc[mt] = zz;
        #pragma unroll
        for (int mt=0;mt<4;++mt) {
            int row = mt*16 + li;
            int sw = (row&7) << 4;
            #pragma unroll
            for (int ks=0;ks<4;++ks) {
                short8 kf = *(const short8*)(sK + row*256 + ((ks*64 + grp*16) ^ sw));
                sacc[mt] = __builtin_amdgcn_mfma_f32_16x16x32_bf16(kf, qf[ks], sacc[mt], 0,0,0);
            }
        }
        if (kt == qt) {  // causal mask on diagonal tile
            int qloc = w*16 + li;
            #pragma unroll
            for (int mt=0;mt<4;++mt)
                #pragma unroll
                for (int r=0;r<4;++r) {
                    int kk = mt*16 + grp*4 + r;
                    if (kk > qloc) sacc[mt][r] = -1e30f;
                }
        }

        // ---- online softmax (per-lane q = li; reduce across grp lanes) ----
        float vmax = -1e30f;
        #pragma unroll
        for (int mt=0;mt<4;++mt)
            #pragma unroll
            for (int r=0;r<4;++r) vmax = fmaxf(vmax, sacc[mt][r]);
        vmax = fmaxf(vmax, __shfl_xor(vmax, 16, 64));
        vmax = fmaxf(vmax, __shfl_xor(vmax, 32, 64));
        float mnew = fmaxf(mrun, vmax);
        float alpha = __expf(mrun - mnew);
        float p[4][4];
        float tsum = 0.f;
        #pragma unroll
        for (int mt=0;mt<4;++mt)
            #pragma unroll
            for (int r=0;r<4;++r) {
                float e = __expf(sacc[mt][r] - mnew);
                p[mt][r] = e;
                tsum += e;
            }
        tsum += __shfl_xor(tsum, 16, 64);
        tsum += __shfl_xor(tsum, 32, 64);
        lrun = lrun * alpha + tsum;
        mrun = mnew;

        // pack P to bf16 pairs: pk[mt][h] = (p[mt][2h], p[mt][2h+1])
        uint32_t pk[4][2];
        #pragma unroll
        for (int mt=0;mt<4;++mt)
            #pragma unroll
            for (int h=0;h<2;++h)
                pk[mt][h] = (uint32_t)f2bf(p[mt][2*h]) | ((uint32_t)f2bf(p[mt][2*h+1]) << 16);

        // redistribute alpha to O rows (q = grp*4 + r)
        float ar[4];
        #pragma unroll
        for (int r=0;r<4;++r) ar[r] = __shfl(alpha, srcBase + r, 64);
        #pragma unroll
        for (int nt=0;nt<8;++nt)
            #pragma unroll
            for (int r=0;r<4;++r) oacc[nt][r] *= ar[r];

        // build PV A-fragments: A[row=li][c = ks2*32 + grp*8 + j]
        short8 pa[2];
        #pragma unroll
        for (int ks2=0;ks2<2;++ks2) {
            union { uint32_t u[4]; short8 s8; } uu;
            #pragma unroll
            for (int i=0;i<4;++i) {
                int grp_s = (grp&1)*2 + (i>>1);
                int src = grp_s*16 + li;
                uint32_t va = (uint32_t)__shfl((int)pk[ks2*2    ][i&1], src, 64);
                uint32_t vb = (uint32_t)__shfl((int)pk[ks2*2 + 1][i&1], src, 64);
                uu.u[i] = (grp < 2) ? va : vb;   // mt_s = ks2*2 + (grp>>1)
            }
            pa[ks2] = uu.s8;
        }

        // ---- O += P · V ----
        #pragma unroll
        for (int nt=0;nt<8;++nt) {
            int row = nt*16 + li;
            int sw = (row&7) << 4;
            #pragma unroll
            for (int ks2=0;ks2<2;++ks2) {
                short8 vf = *(const short8*)(sV + row*128 + ((ks2*64 + grp*16) ^ sw));
                oacc[nt] = __builtin_amdgcn_mfma_f32_16x16x32_bf16(pa[ks2], vf, oacc[nt], 0,0,0);
            }
        }
    }

    // epilogue: divide by l (redistributed to O rows), store fp32
    float lf[4];
    #pragma unroll
    for (int r=0;r<4;++r) lf[r] = 1.0f / __shfl(lrun, srcBase + r, 64);
    float* Ob = Out + bbase;
    #pragma unroll
    for (int nt=0;nt<8;++nt)
        #pragma unroll
        for (int r=0;r<4;++r)
            Ob[(size_t)(q0 + w*16 + grp*4 + r)*H_ + nt*16 + li] = oacc[nt][r] * lf[r];
}

extern "C" void kernel_launch(void* const* d_in, const int* in_sizes, int n_in,
                              void* d_out, int out_size, void* d_ws, size_t ws_size,
                              hipStream_t stream) {
    const float* x  = (const float*)d_in[0];
    const float* Wq = (const float*)d_in[1];
    const float* Wk = (const float*)d_in[2];
    const float* Wv = (const float*)d_in[3];

    unsigned char* ws = (unsigned char*)d_ws;
    unsigned short* Wt  = (unsigned short*)ws;                          // 768 KB
    unsigned short* Qg  = (unsigned short*)(ws + (1u<<20));             // 8 MB
    unsigned short* Kg  = (unsigned short*)(ws + (1u<<20) + 8388608u);  // 8 MB
    unsigned short* Vtg = (unsigned short*)(ws + (1u<<20) + 16777216u); // 8 MB

    prep_w_kernel<<<192, 256, 0, stream>>>(Wq, Wk, Wv, Wt);
    dim3 gp(M_/128, 3);
    proj_kernel<<<gp, 256, 0, stream>>>(x, Wt, Qg, Kg, Vtg);
    dim3 ga(S_/64, B_);
    attn_kernel<<<ga, 256, 0, stream>>>(Qg, Kg, Vtg, (float*)d_out);
}

// Round 5
// 190.890 us; speedup vs baseline: 7.9006x; 1.1060x over previous
//
// v3.0 — attn rebuilt on 32x32x16 MFMA: lane-local softmax (swapped QK^T),
//        O^T=V^T·P^T (q stays on lane), cvt_pk+half-exchange P-repack, defer-max.
#include <hip/hip_runtime.h>
#include <stdint.h>

#define B_ 8
#define S_ 4096
#define E_ 1024
#define H_ 128
#define M_ (B_*S_)

typedef __attribute__((ext_vector_type(8))) short short8;
typedef __attribute__((ext_vector_type(4))) float f32x4;
typedef __attribute__((ext_vector_type(16))) float f32x16;

static constexpr float QSCALE = 0.08838834764831845f; // 1/sqrt(128)

__device__ __forceinline__ unsigned short f2bf(float f) {
    uint32_t u = __float_as_uint(f);
    u += 0x7fffu + ((u >> 16) & 1u);
    return (unsigned short)(u >> 16);
}

__device__ __forceinline__ uint32_t cvt_pk_bf16(float a, float b) {
    uint32_t r;
    asm("v_cvt_pk_bf16_f32 %0, %1, %2" : "=v"(r) : "v"(a), "v"(b));
    return r;
}

// ---------------- W transpose + bf16 convert: Wt[3][128][1024] ----------------
__global__ __launch_bounds__(256)
void prep_w_kernel(const float* __restrict__ Wq, const float* __restrict__ Wk,
                   const float* __restrict__ Wv, unsigned short* __restrict__ Wt)
{
    int id = blockIdx.x*256 + threadIdx.x;        // 0..49151
    int which = id >> 14;
    int rem = id & 16383;
    int h = rem >> 7, kc = rem & 127;
    const float* __restrict__ W = (which==0)?Wq:((which==1)?Wk:Wv);
    const float scale = (which==0)? QSCALE : 1.0f;
    uint32_t u[4];
    #pragma unroll
    for (int p=0;p<4;++p) {
        unsigned short a = f2bf(W[(size_t)(kc*8 + 2*p  )*H_ + h] * scale);
        unsigned short b = f2bf(W[(size_t)(kc*8 + 2*p+1)*H_ + h] * scale);
        u[p] = (uint32_t)a | ((uint32_t)b << 16);
    }
    uint4 v; v.x=u[0]; v.y=u[1]; v.z=u[2]; v.w=u[3];
    *(uint4*)(Wt + (size_t)(which*H_ + h)*E_ + kc*8) = v;
}

// ---------------- QKV projection, bf16 MFMA (unchanged, verified) ----------------
__global__ __launch_bounds__(256)
void proj_kernel(const float* __restrict__ x, const unsigned short* __restrict__ Wt,
                 unsigned short* __restrict__ Qg, unsigned short* __restrict__ Kg,
                 unsigned short* __restrict__ Vtg)
{
    const int t = threadIdx.x;
    const int w = t >> 6, l = t & 63;
    const int grp = l >> 4, li = l & 15;
    const int rb = blockIdx.x;
    const int which = blockIdx.y;
    const int row0 = rb * 128;

    __shared__ __align__(128) unsigned char smem[34816];
    unsigned char* sX = smem;
    unsigned char* sW = smem + 16384;
    unsigned char* epi = smem;

    const unsigned char* Wslice = (const unsigned char*)(Wt + (size_t)which*H_*E_);

    f32x4 acc[2][8];
    const f32x4 zz = {0.f,0.f,0.f,0.f};
    #pragma unroll
    for (int mt=0;mt<2;++mt)
        #pragma unroll
        for (int nt=0;nt<8;++nt) acc[mt][nt] = zz;

    for (int k0=0; k0<E_; k0+=64) {
        __syncthreads();
        #pragma unroll
        for (int i=0;i<8;++i) {
            int idx = i*256 + t;
            int row = idx >> 4, c4 = idx & 15;
            float4 v = *(const float4*)(x + (size_t)(row0+row)*E_ + k0 + c4*4);
            uint32_t lo = (uint32_t)f2bf(v.x) | ((uint32_t)f2bf(v.y)<<16);
            uint32_t hi2 = (uint32_t)f2bf(v.z) | ((uint32_t)f2bf(v.w)<<16);
            uint2 pv; pv.x = lo; pv.y = hi2;
            *(uint2*)(sX + row*128 + ((c4*8) ^ ((row&7)<<4))) = pv;
        }
        #pragma unroll
        for (int i=0;i<4;++i) {
            int c = i*256 + t;
            int h = c >> 3, cb = (c & 7) * 16;
            uint4 v = *(const uint4*)(Wslice + (size_t)h*2048 + k0*2 + cb);
            *(uint4*)(sW + h*128 + (cb ^ ((h&7)<<4))) = v;
        }
        __syncthreads();
        #pragma unroll
        for (int ks=0;ks<2;++ks) {
            short8 af[2], bf[8];
            #pragma unroll
            for (int mt=0;mt<2;++mt) {
                int row = w*32 + mt*16 + li;
                af[mt] = *(const short8*)(sX + row*128 + ((ks*64 + grp*16) ^ ((row&7)<<4)));
            }
            #pragma unroll
            for (int nt=0;nt<8;++nt) {
                int rh = nt*16 + li;
                bf[nt] = *(const short8*)(sW + rh*128 + ((ks*64 + grp*16) ^ ((rh&7)<<4)));
            }
            #pragma unroll
            for (int mt=0;mt<2;++mt)
                #pragma unroll
                for (int nt=0;nt<8;++nt)
                    acc[mt][nt] = __builtin_amdgcn_mfma_f32_16x16x32_bf16(af[mt], bf[nt], acc[mt][nt], 0,0,0);
        }
    }

    __syncthreads();
    const int base = w * 8704;
    #pragma unroll
    for (int mt=0;mt<2;++mt)
        #pragma unroll
        for (int nt=0;nt<8;++nt)
            #pragma unroll
            for (int r=0;r<4;++r) {
                int rowl = mt*16 + grp*4 + r;
                int col  = nt*16 + li;
                *(unsigned short*)(epi + base + rowl*272 + col*2) = f2bf(acc[mt][nt][r]);
            }
    __syncthreads();

    if (which < 2) {
        unsigned short* O = (which==0)? Qg : Kg;
        #pragma unroll
        for (int i=0;i<8;++i) {
            int idx = i*64 + l;
            int rowl = idx >> 4, cc = idx & 15;
            uint4 v = *(const uint4*)(epi + base + rowl*272 + cc*16);
            int row_g = row0 + w*32 + rowl;
            *(uint4*)((unsigned char*)O + (size_t)row_g*256 + cc*16) = v;
        }
    } else {
        const int bidx = rb >> 5;
        const int srow = (rb & 31) * 128 + w*32;
        #pragma unroll
        for (int i=0;i<8;++i) {
            int idx = i*64 + l;
            int h = idx >> 2, sc = idx & 3;
            uint32_t u[4];
            #pragma unroll
            for (int p=0;p<4;++p) {
                unsigned short a = *(const unsigned short*)(epi + base + (sc*8 + 2*p  )*272 + h*2);
                unsigned short b = *(const unsigned short*)(epi + base + (sc*8 + 2*p+1)*272 + h*2);
                u[p] = (uint32_t)a | ((uint32_t)b << 16);
            }
            uint4 v; v.x=u[0]; v.y=u[1]; v.z=u[2]; v.w=u[3];
            *(uint4*)(Vtg + (size_t)(bidx*H_ + h)*S_ + srow + sc*8) = v;
        }
    }
}

// ---------------- Flash attention v3: 32x32x16 MFMA ----------------
// grid (S_/64, B_), block 128 (2 waves x 32 q-rows). KV-tile 64.
// Lane owns query q = q0 + w*32 + (l&31); halves (l>>5) split the key dim.
__global__ __launch_bounds__(128, 1)
void attn_kernel(const unsigned short* __restrict__ Qg,
                 const unsigned short* __restrict__ Kg,
                 const unsigned short* __restrict__ Vtg,
                 float* __restrict__ Out)
{
    const int t   = threadIdx.x;
    const int w   = t >> 6;        // wave 0/1
    const int l   = t & 63;
    const int hi  = l >> 5;        // half of wave
    const int c31 = l & 31;        // MFMA col index = this lane's query
    const int qt  = (S_/64 - 1) - blockIdx.x;   // reverse: long blocks first
    const int b   = blockIdx.y;
    const int q0  = qt * 64;
    const int qrow = q0 + w*32 + c31;

    __shared__ __align__(128) unsigned char sK[16384];  // [64 keys][128k] bf16, 256B rows, XOR-swz
    __shared__ __align__(128) unsigned char sV[16384];  // Vt [128h][64s] bf16, 128B rows, XOR-swz

    const size_t bbase = (size_t)b * S_ * H_;

    // Q fragments: qf[ks] = Q[qrow][ks*16 + hi*8 .. +8)  (B-operand halves)
    short8 qf[8];
    {
        const unsigned short* qp = Qg + bbase + (size_t)qrow * H_;
        #pragma unroll
        for (int ks=0; ks<8; ++ks)
            qf[ks] = *(const short8*)(qp + ks*16 + hi*8);
    }

    f32x16 oacc[4];   // O^T tiles: oacc[ht], rows h = ht*32 + (r&3)+8*(r>>2)+4*hi, col q
    #pragma unroll
    for (int ht=0; ht<4; ++ht)
        #pragma unroll
        for (int r=0; r<16; ++r) oacc[ht][r] = 0.f;
    float mrun = -1e30f, lrun = 0.f;

    const unsigned char* Kb = (const unsigned char*)(Kg + bbase);
    const unsigned char* Vb = (const unsigned char*)(Vtg + (size_t)b*H_*S_);
    const int swzq = (c31 & 7) << 4;

    for (int kt=0; kt<=qt; ++kt) {
        __syncthreads();
        // stage K tile [64][128] bf16, swizzled
        #pragma unroll
        for (int i=0;i<8;++i) {
            int c = i*128 + t;
            int row = c >> 4, cb = (c & 15) * 16;
            *(uint4*)(sK + row*256 + (cb ^ ((row&7)<<4))) =
                *(const uint4*)(Kb + (size_t)(kt*64 + row)*256 + cb);
        }
        // stage Vt tile [128][64] bf16, swizzled
        #pragma unroll
        for (int i=0;i<8;++i) {
            int c = i*128 + t;
            int h = c >> 3, cb = (c & 7) * 16;
            *(uint4*)(sV + h*128 + (cb ^ ((h&7)<<4))) =
                *(const uint4*)(Vb + (size_t)h*(S_*2) + kt*128 + cb);
        }
        __syncthreads();

        // ---- S^T = K · Q^T : D[key][q], lane col = q ----
        f32x16 sacc[2];
        #pragma unroll
        for (int st=0; st<2; ++st)
            #pragma unroll
            for (int r=0; r<16; ++r) sacc[st][r] = 0.f;
        #pragma unroll
        for (int st=0; st<2; ++st) {
            int krow = st*32 + c31;
            #pragma unroll
            for (int ks=0; ks<8; ++ks) {
                short8 kf = *(const short8*)(sK + krow*256 + ((ks*32 + hi*16) ^ swzq));
                sacc[st] = __builtin_amdgcn_mfma_f32_32x32x16_bf16(kf, qf[ks], sacc[st], 0,0,0);
            }
        }

        if (kt == qt) {  // causal mask on diagonal tile
            #pragma unroll
            for (int st=0; st<2; ++st)
                #pragma unroll
                for (int r=0; r<16; ++r) {
                    int key = q0 + st*32 + (r&3) + 8*(r>>2) + 4*hi;
                    if (key > qrow) sacc[st][r] = -1e30f;
                }
        }

        // ---- online softmax: per-lane (one q), + 1 half-exchange ----
        float pmax = -1e30f;
        #pragma unroll
        for (int st=0; st<2; ++st)
            #pragma unroll
            for (int r=0; r<16; ++r) pmax = fmaxf(pmax, sacc[st][r]);
        pmax = fmaxf(pmax, __shfl_xor(pmax, 32, 64));

        if (!__all(pmax - mrun <= 8.0f)) {   // defer-max (T13)
            float mnew = fmaxf(mrun, pmax);
            float alpha = __expf(mrun - mnew);
            #pragma unroll
            for (int ht=0; ht<4; ++ht)
                #pragma unroll
                for (int r=0; r<16; ++r) oacc[ht][r] *= alpha;
            lrun *= alpha;
            mrun = mnew;
        }

        float p[2][16];
        float psum = 0.f;
        #pragma unroll
        for (int st=0; st<2; ++st)
            #pragma unroll
            for (int r=0; r<16; ++r) {
                float e = __expf(sacc[st][r] - mrun);
                p[st][r] = e;
                psum += e;
            }
        psum += __shfl_xor(psum, 32, 64);
        lrun += psum;

        // ---- pack P -> bf16 B-frags (P^T), half-exchange via shfl_xor(32) ----
        short8 pf[4];   // pf[sl] covers keys sl*16 .. sl*16+15
        #pragma unroll
        for (int st=0; st<2; ++st) {
            uint32_t A0 = cvt_pk_bf16(p[st][0],  p[st][1]);
            uint32_t A1 = cvt_pk_bf16(p[st][2],  p[st][3]);
            uint32_t B0 = cvt_pk_bf16(p[st][4],  p[st][5]);
            uint32_t B1 = cvt_pk_bf16(p[st][6],  p[st][7]);
            uint32_t C0 = cvt_pk_bf16(p[st][8],  p[st][9]);
            uint32_t C1 = cvt_pk_bf16(p[st][10], p[st][11]);
            uint32_t D0 = cvt_pk_bf16(p[st][12], p[st][13]);
            uint32_t D1 = cvt_pk_bf16(p[st][14], p[st][15]);
            // slice 0: keys st*32 + [0,16)
            {
                uint32_t x0 = hi ? A0 : B0;
                uint32_t x1 = hi ? A1 : B1;
                uint32_t y0 = (uint32_t)__shfl_xor((int)x0, 32, 64);
                uint32_t y1 = (uint32_t)__shfl_xor((int)x1, 32, 64);
                union { uint32_t u[4]; short8 s; } uu;
                uu.u[0] = hi ? y0 : A0;
                uu.u[1] = hi ? y1 : A1;
                uu.u[2] = hi ? B0 : y0;
                uu.u[3] = hi ? B1 : y1;
                pf[st*2] = uu.s;
            }
            // slice 1: keys st*32 + [16,32)
            {
                uint32_t x0 = hi ? C0 : D0;
                uint32_t x1 = hi ? C1 : D1;
                uint32_t y0 = (uint32_t)__shfl_xor((int)x0, 32, 64);
                uint32_t y1 = (uint32_t)__shfl_xor((int)x1, 32, 64);
                union { uint32_t u[4]; short8 s; } uu;
                uu.u[0] = hi ? y0 : C0;
                uu.u[1] = hi ? y1 : C1;
                uu.u[2] = hi ? D0 : y0;
                uu.u[3] = hi ? D1 : y1;
                pf[st*2+1] = uu.s;
            }
        }

        // ---- O^T += V^T · P^T ----
        #pragma unroll
        for (int sl=0; sl<4; ++sl) {
            #pragma unroll
            for (int ht=0; ht<4; ++ht) {
                int h = ht*32 + c31;
                short8 vf = *(const short8*)(sV + h*128 + ((sl*32 + hi*16) ^ swzq));
                oacc[ht] = __builtin_amdgcn_mfma_f32_32x32x16_bf16(vf, pf[sl], oacc[ht], 0,0,0);
            }
        }
    }

    // epilogue: O[q][h] = oacc^T / l ; regs 4k..4k+3 are consecutive h
    float linv = 1.0f / lrun;
    float* Op = Out + bbase + (size_t)qrow * H_;
    #pragma unroll
    for (int ht=0; ht<4; ++ht)
        #pragma unroll
        for (int k=0; k<4; ++k) {
            float4 o;
            o.x = oacc[ht][4*k+0] * linv;
            o.y = oacc[ht][4*k+1] * linv;
            o.z = oacc[ht][4*k+2] * linv;
            o.w = oacc[ht][4*k+3] * linv;
            *(float4*)(Op + ht*32 + 8*k + 4*hi) = o;
        }
}

extern "C" void kernel_launch(void* const* d_in, const int* in_sizes, int n_in,
                              void* d_out, int out_size, void* d_ws, size_t ws_size,
                              hipStream_t stream) {
    const float* x  = (const float*)d_in[0];
    const float* Wq = (const float*)d_in[1];
    const float* Wk = (const float*)d_in[2];
    const float* Wv = (const float*)d_in[3];

    unsigned char* ws = (unsigned char*)d_ws;
    unsigned short* Wt  = (unsigned short*)ws;                          // 768 KB
    unsigned short* Qg  = (unsigned short*)(ws + (1u<<20));             // 8 MB
    unsigned short* Kg  = (unsigned short*)(ws + (1u<<20) + 8388608u);  // 8 MB
    unsigned short* Vtg = (unsigned short*)(ws + (1u<<20) + 16777216u); // 8 MB

    prep_w_kernel<<<192, 256, 0, stream>>>(Wq, Wk, Wv, Wt);
    dim3 gp(M_/128, 3);
    proj_kernel<<<gp, 256, 0, stream>>>(x, Wt, Qg, Kg, Vtg);
    dim3 ga(S_/64, B_);
    attn_kernel<<<ga, 128, 0, stream>>>(Qg, Kg, Vtg, (float*)d_out);
}